// Round 5
// baseline (212.335 us; speedup 1.0000x reference)
//
#include <hip/hip_runtime.h>
#include <hip/hip_bf16.h>

// Problem constants
#define BB 2
#define SS 2048
#define DD 64
#define HH 8
#define HD 512            // HH*DD
#define SCALE 0.125f      // 1/sqrt(64)

typedef __bf16 bf16;
typedef __attribute__((ext_vector_type(4))) __bf16 bf16x4;
typedef __attribute__((ext_vector_type(8))) __bf16 bf16x8;
typedef __attribute__((ext_vector_type(4))) float floatx4;

#define SLOTSTRIDE 2097152   // BB*SS*HD floats per split-K partial slot

__device__ __forceinline__ floatx4 mfma16(bf16x8 a, bf16x8 b, floatx4 c) {
    return __builtin_amdgcn_mfma_f32_16x16x32_bf16(a, b, c, 0, 0, 0);
}

__device__ __forceinline__ bf16x8 load8(const void* base, size_t idx, int f32) {
    if (f32) {
        const float* p = (const float*)base + idx;
        const float4 a = *reinterpret_cast<const float4*>(p);
        const float4 b = *reinterpret_cast<const float4*>(p + 4);
        bf16x8 r;
        r[0] = (bf16)a.x; r[1] = (bf16)a.y; r[2] = (bf16)a.z; r[3] = (bf16)a.w;
        r[4] = (bf16)b.x; r[5] = (bf16)b.y; r[6] = (bf16)b.z; r[7] = (bf16)b.w;
        return r;
    }
    return *reinterpret_cast<const bf16x8*>((const bf16*)base + idx);
}

__device__ __forceinline__ float load1(const void* base, int idx, int f32) {
    return f32 ? ((const float*)base)[idx] : (float)((const bf16*)base)[idx];
}

// pack two fp32 -> one dword holding two bf16 (lo=first)
__device__ __forceinline__ unsigned packbf(float a, float b) {
    union { unsigned u; __bf16 h[2]; } c;
    c.h[0] = (bf16)a; c.h[1] = (bf16)b;
    return c.u;
}

// ---------------------------------------------------------------------------
// Kernel 0: dtype detection (bf16 N(0,1) never has exp field >= 134).
// ---------------------------------------------------------------------------
__global__ __launch_bounds__(64) void detect_kernel(const unsigned short* __restrict__ q,
                                                    int* __restrict__ flag) {
    int hit = 0;
    for (int i = threadIdx.x; i < 8192; i += 64) {
        const unsigned short u = q[i];
        if (((u >> 7) & 0xFF) >= 134) hit = 1;
    }
    const unsigned long long m = __ballot(hit);
    if (threadIdx.x == 0) *flag = (m != 0ull) ? 1 : 0;
}

// ---------------------------------------------------------------------------
// Kernel 1: QKV projection (MFMA) + RoPE (HW v_sin/v_cos) + fp32 norms +
// vectorized V transpose.
// ---------------------------------------------------------------------------
__global__ __launch_bounds__(64) void proj_rope_kernel(
    const void* __restrict__ q, const void* __restrict__ Wq,
    const void* __restrict__ Wk, const void* __restrict__ Wv,
    bf16* __restrict__ qh, bf16* __restrict__ kh, bf16* __restrict__ vt,
    float* __restrict__ qn, float* __restrict__ kn,
    const int* __restrict__ flagp)
{
    const int f32  = *flagp;
    const int lane = threadIdx.x;
    const int l16  = lane & 15;
    const int quad = lane >> 4;

    int id = blockIdx.x;                 // ((w*BB + b)*(SS/16) + st)*HH + h
    const int h  = id % HH; id /= HH;
    const int st = id % (SS / 16); id /= (SS / 16);
    const int b  = id % BB; id /= BB;
    const int w  = id;                   // 0=q, 1=k, 2=v
    const int s0 = st * 16;

    const void* W = (w == 0) ? Wq : (w == 1) ? Wk : Wv;

    const size_t qrow = ((size_t)b * SS + s0 + l16) * DD;
    bf16x8 a0 = load8(q, qrow + quad * 8, f32);
    bf16x8 a1 = load8(q, qrow + quad * 8 + 32, f32);

    floatx4 cv[4];
#pragma unroll
    for (int t = 0; t < 4; ++t) {
        const size_t wrow = (size_t)(h * 64 + t * 16 + l16) * DD;
        bf16x8 b0 = load8(W, wrow + quad * 8, f32);
        bf16x8 b1 = load8(W, wrow + quad * 8 + 32, f32);
        floatx4 acc = {0.f, 0.f, 0.f, 0.f};
        acc = mfma16(a0, b0, acc);
        acc = mfma16(a1, b1, acc);
        cv[t] = acc;
    }

    const size_t bh = (size_t)b * HH + h;

    if (w < 2) {
        bf16*  dst  = (w == 0) ? qh : kh;
        float* ndst = (w == 0) ? qn : kn;
        float nacc[4] = {0.f, 0.f, 0.f, 0.f};
#pragma unroll
        for (int t = 0; t < 4; ++t) {
            const int d    = t * 16 + l16;
            const int twoi = d & ~1;
            const float frev = __builtin_amdgcn_exp2f(
                -(float)twoi * (13.2877123795f / 64.0f)) * 0.15915494309f;
            const bool odd = (d & 1);
#pragma unroll
            for (int r = 0; r < 4; ++r) {
                float v = cv[t][r];
                float partner = __shfl_xor(v, 1);
                const int srow = s0 + quad * 4 + r;
                float rev = (float)srow * frev;       // revolutions
                rev -= floorf(rev);
                float sn = __builtin_amdgcn_sinf(rev);
                float cs = __builtin_amdgcn_cosf(rev);
                float res = odd ? (partner * sn + v * cs)
                                : (v * cs - partner * sn);
                nacc[r] += res * res;
                dst[(bh * SS + srow) * DD + d] = (bf16)res;
            }
        }
#pragma unroll
        for (int off = 1; off < 16; off <<= 1)
#pragma unroll
            for (int r = 0; r < 4; ++r)
                nacc[r] += __shfl_xor(nacc[r], off);
        if (l16 == 0)
#pragma unroll
            for (int r = 0; r < 4; ++r)
                ndst[bh * SS + s0 + quad * 4 + r] = nacc[r];
    } else {
#pragma unroll
        for (int t = 0; t < 4; ++t) {
            const int d = t * 16 + l16;
            bf16x4 pv;
#pragma unroll
            for (int r = 0; r < 4; ++r) pv[r] = (bf16)cv[t][r];
            *reinterpret_cast<bf16x4*>(vt + (bh * DD + d) * SS + s0 + quad * 4) = pv;
        }
    }
}

// ---------------------------------------------------------------------------
// Kernel 2: causal distance-kernel attention, split-K, BARRIER-FREE.
// S^T = K·Q^T (operand-swapped MFMA, same register data). C-frag -> PV B-frag
// via a conflict-free 4-shuffle permutation network (no LDS, no barriers):
//   source lane (sq,l16) holds pk00,pk01 (sub0 keys sq*4+{0,1},{2,3}) and
//   pk10,pk11 (sub1). Dest (q,l16) needs keys 8q..8q+7 of query l16.
//   shuffle0/1: src = l16 + bitrev2(q)*16,   val = sq&1 ? pk1x : pk0x
//   shuffle2/3: src = l16 + (bitrev2(q)^1)*16, val = sq&1 ? pk0x : pk1x
//   dest dwords = q<2 ? (s0,s1,s2,s3) : (s2,s3,s0,s1).   [verified all quads]
// O^T = V^T·P^T accumulated in C-frags (col=query, row=d).
// ---------------------------------------------------------------------------
__global__ __launch_bounds__(64) void attn_kernel(
    const bf16* __restrict__ qh, const bf16* __restrict__ kh,
    const bf16* __restrict__ vt, const float* __restrict__ qn,
    const float* __restrict__ kn, const void* __restrict__ gamma,
    float* __restrict__ partial, const int* __restrict__ flagp, int ksh)
{
    const int f32  = *flagp;
    const int lane = threadIdx.x;
    const int l16  = lane & 15;
    const int quad = lane >> 4;

    int id = blockIdx.x;
    const int qt   = id & 127; id >>= 7;
    const int slot = id & 3;   id >>= 2;
    const int h    = id % HH;
    const int b    = id / HH;
    const int s0   = qt * 16;
    const int tb   = slot << ksh;
    if (tb > s0 + 15) return;                       // slot fully acausal
    const int te_r = min(tb + (1 << ksh), (s0 + 16 + 31) & ~31);
    const int nch  = (te_r - tb) >> 5;              // 32-key chunks (tail masked)
    const size_t bh = (size_t)b * HH + h;

    // p = exp(-gs*max(raw,0)) = exp2(min(-cc*raw, 0)),  cc = gs*log2(e) >= 0
    const float cc = load1(gamma, h, f32) * SCALE * 1.4426950408889634f;

    const bf16* qbase = qh + (bh * SS + s0 + l16) * DD;
    bf16x8 aq0 = *reinterpret_cast<const bf16x8*>(qbase + quad * 8);
    bf16x8 aq1 = *reinterpret_cast<const bf16x8*>(qbase + quad * 8 + 32);
    const float qn_l = qn[bh * SS + s0 + l16];

    // transpose network constants
    const int mq   = ((quad & 1) << 1) | (quad >> 1);   // bitrev2(quad)
    const int srcA = l16 + mq * 16;
    const int srcB = l16 + (mq ^ 1) * 16;
    const bool oddq = (quad & 1);

    floatx4 acc[4];
#pragma unroll
    for (int nb = 0; nb < 4; ++nb) acc[nb] = (floatx4){0.f, 0.f, 0.f, 0.f};

    const bf16* kbase   = kh + (bh * SS + l16) * DD;      // + key*DD
    const float* knbase = kn + bh * SS + quad * 4;        // + key
    const bf16* vb[4];
#pragma unroll
    for (int nb = 0; nb < 4; ++nb)
        vb[nb] = vt + (bh * DD + nb * 16 + l16) * SS + quad * 8;  // + key

    // preload chunk 0: K rows + kn
    bf16x8 kc0 = *reinterpret_cast<const bf16x8*>(kbase + (size_t)tb * DD + quad * 8);
    bf16x8 kc1 = *reinterpret_cast<const bf16x8*>(kbase + (size_t)tb * DD + quad * 8 + 32);
    bf16x8 kc2 = *reinterpret_cast<const bf16x8*>(kbase + (size_t)(tb + 16) * DD + quad * 8);
    bf16x8 kc3 = *reinterpret_cast<const bf16x8*>(kbase + (size_t)(tb + 16) * DD + quad * 8 + 32);
    float4 knA = *reinterpret_cast<const float4*>(knbase + tb);
    float4 knB = *reinterpret_cast<const float4*>(knbase + tb + 16);

    int t0 = tb;
    for (int c = 0; c < nch; ++c, t0 += 32) {
        // V loads for this chunk (consumed at the end -> latency covered)
        bf16x8 vv0 = *reinterpret_cast<const bf16x8*>(vb[0] + t0);
        bf16x8 vv1 = *reinterpret_cast<const bf16x8*>(vb[1] + t0);
        bf16x8 vv2 = *reinterpret_cast<const bf16x8*>(vb[2] + t0);
        bf16x8 vv3 = *reinterpret_cast<const bf16x8*>(vb[3] + t0);

        // prefetch next chunk's K + kn
        bf16x8 nk0, nk1, nk2, nk3; float4 nknA, nknB;
        if (c + 1 < nch) {
            const int t1 = t0 + 32;
            nk0 = *reinterpret_cast<const bf16x8*>(kbase + (size_t)t1 * DD + quad * 8);
            nk1 = *reinterpret_cast<const bf16x8*>(kbase + (size_t)t1 * DD + quad * 8 + 32);
            nk2 = *reinterpret_cast<const bf16x8*>(kbase + (size_t)(t1 + 16) * DD + quad * 8);
            nk3 = *reinterpret_cast<const bf16x8*>(kbase + (size_t)(t1 + 16) * DD + quad * 8 + 32);
            nknA = *reinterpret_cast<const float4*>(knbase + t1);
            nknB = *reinterpret_cast<const float4*>(knbase + t1 + 16);
        }

        // S^T: row=key=quad*4+r (+16 for sub1), col=query=l16
        floatx4 zt0 = {0.f, 0.f, 0.f, 0.f};
        zt0 = mfma16(kc0, aq0, zt0);
        zt0 = mfma16(kc1, aq1, zt0);
        floatx4 zt1 = {0.f, 0.f, 0.f, 0.f};
        zt1 = mfma16(kc2, aq0, zt1);
        zt1 = mfma16(kc3, aq1, zt1);

        unsigned pk00, pk01, pk10, pk11;
        if (t0 + 31 <= s0) {                 // fully causal chunk: no mask
            float p0[4], p1[4];
#pragma unroll
            for (int r = 0; r < 4; ++r) {
                float rawA = fmaf(-2.f, zt0[r], qn_l + ((const float*)&knA)[r]);
                float rawB = fmaf(-2.f, zt1[r], qn_l + ((const float*)&knB)[r]);
                p0[r] = __builtin_amdgcn_exp2f(fminf(-cc * rawA, 0.f));
                p1[r] = __builtin_amdgcn_exp2f(fminf(-cc * rawB, 0.f));
            }
            pk00 = packbf(p0[0], p0[1]); pk01 = packbf(p0[2], p0[3]);
            pk10 = packbf(p1[0], p1[1]); pk11 = packbf(p1[2], p1[3]);
        } else {                             // diagonal chunk: per-lane mask
            const int dq2 = s0 + l16 - t0 - quad * 4;   // key_local <= dq2
            float p0[4], p1[4];
#pragma unroll
            for (int r = 0; r < 4; ++r) {
                float rawA = fmaf(-2.f, zt0[r], qn_l + ((const float*)&knA)[r]);
                float rawB = fmaf(-2.f, zt1[r], qn_l + ((const float*)&knB)[r]);
                float eA = __builtin_amdgcn_exp2f(fminf(-cc * rawA, 0.f));
                float eB = __builtin_amdgcn_exp2f(fminf(-cc * rawB, 0.f));
                p0[r] = (r <= dq2)      ? eA : 0.f;
                p1[r] = (16 + r <= dq2) ? eB : 0.f;
            }
            pk00 = packbf(p0[0], p0[1]); pk01 = packbf(p0[2], p0[3]);
            pk10 = packbf(p1[0], p1[1]); pk11 = packbf(p1[2], p1[3]);
        }

        // conflict-free transpose network (see header comment)
        const unsigned vA = oddq ? pk10 : pk00;
        const unsigned vB = oddq ? pk11 : pk01;
        const unsigned vC = oddq ? pk00 : pk10;
        const unsigned vD = oddq ? pk01 : pk11;
        const int sh0 = __shfl((int)vA, srcA);
        const int sh1 = __shfl((int)vB, srcA);
        const int sh2 = __shfl((int)vC, srcB);
        const int sh3 = __shfl((int)vD, srcB);
        const bool lo = (quad < 2);
        union { int4 i4; bf16x8 v; } bu;
        bu.i4 = make_int4(lo ? sh0 : sh2, lo ? sh1 : sh3,
                          lo ? sh2 : sh0, lo ? sh3 : sh1);

        acc[0] = mfma16(vv0, bu.v, acc[0]);
        acc[1] = mfma16(vv1, bu.v, acc[1]);
        acc[2] = mfma16(vv2, bu.v, acc[2]);
        acc[3] = mfma16(vv3, bu.v, acc[3]);

        if (c + 1 < nch) {
            kc0 = nk0; kc1 = nk1; kc2 = nk2; kc3 = nk3;
            knA = nknA; knB = nknB;
        }
    }

    // O^T C-frag: col=query=l16, row=d_local=quad*4+r -> float4 per nb
    float* pb = partial + (size_t)slot * SLOTSTRIDE
              + ((size_t)b * SS + s0 + l16) * HD + h * 64 + quad * 4;
#pragma unroll
    for (int nb = 0; nb < 4; ++nb) {
        float4 o;
        o.x = acc[nb][0]; o.y = acc[nb][1]; o.z = acc[nb][2]; o.w = acc[nb][3];
        *reinterpret_cast<float4*>(pb + nb * 16) = o;
    }
}

// ---------------------------------------------------------------------------
// Kernel 3: fused split-K reduce + output projection, slot count templated.
// ---------------------------------------------------------------------------
template <int NACT>
__device__ __forceinline__ floatx4 opj_core(const float* pp, const void* Wo,
                                            size_t brow, int f32, int quad) {
    floatx4 acc = {0.f, 0.f, 0.f, 0.f};
#pragma unroll 2
    for (int kk = 0; kk < HD; kk += 32) {
        const float* p0 = pp + kk;
        float4 u0 = *reinterpret_cast<const float4*>(p0);
        float4 u1 = *reinterpret_cast<const float4*>(p0 + 4);
#pragma unroll
        for (int s = 1; s < NACT; ++s) {
            const float* ps = p0 + (size_t)s * SLOTSTRIDE;
            const float4 w0 = *reinterpret_cast<const float4*>(ps);
            const float4 w1 = *reinterpret_cast<const float4*>(ps + 4);
            u0.x += w0.x; u0.y += w0.y; u0.z += w0.z; u0.w += w0.w;
            u1.x += w1.x; u1.y += w1.y; u1.z += w1.z; u1.w += w1.w;
        }
        bf16x8 a;
        a[0] = (bf16)u0.x; a[1] = (bf16)u0.y; a[2] = (bf16)u0.z; a[3] = (bf16)u0.w;
        a[4] = (bf16)u1.x; a[5] = (bf16)u1.y; a[6] = (bf16)u1.z; a[7] = (bf16)u1.w;
        bf16x8 bb = load8(Wo, brow + kk, f32);
        acc = mfma16(a, bb, acc);
    }
    return acc;
}

__global__ __launch_bounds__(64) void outproj_kernel(
    const float* __restrict__ partial, const void* __restrict__ Wo,
    void* __restrict__ out, const int* __restrict__ flagp, int ksh)
{
    const int f32  = *flagp;
    const int lane = threadIdx.x;
    const int l16  = lane & 15;
    const int quad = lane >> 4;
    const int ct = blockIdx.x & 3;
    const int rt = blockIdx.x >> 2;

    const int g0 = rt * 16;              // global row (b*SS + s)
    const int s0 = g0 & (SS - 1);
    const int nact = (s0 + 16 + (1 << ksh) - 1) >> ksh;

    const float* pp = partial + (size_t)(g0 + l16) * HD + quad * 8;
    const size_t brow = (size_t)(ct * 16 + l16) * HD + quad * 8;

    floatx4 acc;
    switch (nact) {
        case 1:  acc = opj_core<1>(pp, Wo, brow, f32, quad); break;
        case 2:  acc = opj_core<2>(pp, Wo, brow, f32, quad); break;
        case 3:  acc = opj_core<3>(pp, Wo, brow, f32, quad); break;
        default: acc = opj_core<4>(pp, Wo, brow, f32, quad); break;
    }

#pragma unroll
    for (int r = 0; r < 4; ++r) {
        const size_t o = (size_t)(g0 + quad * 4 + r) * DD + ct * 16 + l16;
        if (f32) ((float*)out)[o] = acc[r];
        else     ((bf16*)out)[o]  = (bf16)acc[r];
    }
}

// ---------------------------------------------------------------------------
extern "C" void kernel_launch(void* const* d_in, const int* in_sizes, int n_in,
                              void* d_out, int out_size, void* d_ws, size_t ws_size,
                              hipStream_t stream) {
    const void* q     = d_in[0];
    const void* Wq    = d_in[1];
    const void* Wk    = d_in[2];
    const void* Wv    = d_in[3];
    const void* Wo    = d_in[4];
    const void* gamma = d_in[5];

    char* ws = (char*)d_ws;
    bf16*  qh      = (bf16*)(ws);                    // 4 MiB
    bf16*  kh      = (bf16*)(ws + 4194304);          // 4 MiB
    bf16*  vt      = (bf16*)(ws + 8388608);          // 4 MiB
    float* qn      = (float*)(ws + 12582912);        // 128 KiB
    float* kn      = (float*)(ws + 12713984);        // 128 KiB
    int*   flag    = (int*)  (ws + 12845056);
    float* partial = (float*)(ws + 13631488);        // nslot x 8 MiB

    // split-K tier by available workspace: 4 / 2 / 1 slots
    int ksh = 11;
    if (ws_size >= 13631488ull + 4ull * 8388608ull)      ksh = 9;
    else if (ws_size >= 13631488ull + 2ull * 8388608ull) ksh = 10;

    detect_kernel<<<dim3(1), dim3(64), 0, stream>>>((const unsigned short*)q, flag);
    proj_rope_kernel<<<dim3(3 * BB * (SS / 16) * HH), dim3(64), 0, stream>>>(
        q, Wq, Wk, Wv, qh, kh, vt, qn, kn, flag);
    attn_kernel<<<dim3(BB * HH * 4 * (SS / 16)), dim3(64), 0, stream>>>(
        qh, kh, vt, qn, kn, gamma, partial, flag, ksh);
    outproj_kernel<<<dim3((BB * SS / 16) * 4), dim3(64), 0, stream>>>(
        partial, Wo, d_out, flag, ksh);
}

// Round 6
// 208.227 us; speedup vs baseline: 1.0197x; 1.0197x over previous
//
#include <hip/hip_runtime.h>
#include <hip/hip_bf16.h>

// Problem constants
#define BB 2
#define SS 2048
#define DD 64
#define HH 8
#define HD 512            // HH*DD
#define SCALE 0.125f      // 1/sqrt(64)

typedef __bf16 bf16;
typedef __attribute__((ext_vector_type(4))) __bf16 bf16x4;
typedef __attribute__((ext_vector_type(8))) __bf16 bf16x8;
typedef __attribute__((ext_vector_type(4))) float floatx4;

#define PSLOT 2097152     // bf16 elements per partial slot = BB*HH*SS*DD (4 MiB)

__device__ __forceinline__ floatx4 mfma16(bf16x8 a, bf16x8 b, floatx4 c) {
    return __builtin_amdgcn_mfma_f32_16x16x32_bf16(a, b, c, 0, 0, 0);
}

// v_mfma_f32_16x16x16_bf16: A 2 VGPRs (4 bf16), B 2 VGPRs, C/D 4 VGPRs.
// ISA-documented on gfx950; no builtin-name risk via inline asm.
#define PV_MFMA(ACC, A, B) \
    asm volatile("v_mfma_f32_16x16x16_bf16 %0, %1, %2, %0" \
                 : "+v"(ACC) : "v"(A), "v"(B))

__device__ __forceinline__ bf16x8 load8(const void* base, size_t idx, int f32) {
    if (f32) {
        const float* p = (const float*)base + idx;
        const float4 a = *reinterpret_cast<const float4*>(p);
        const float4 b = *reinterpret_cast<const float4*>(p + 4);
        bf16x8 r;
        r[0] = (bf16)a.x; r[1] = (bf16)a.y; r[2] = (bf16)a.z; r[3] = (bf16)a.w;
        r[4] = (bf16)b.x; r[5] = (bf16)b.y; r[6] = (bf16)b.z; r[7] = (bf16)b.w;
        return r;
    }
    return *reinterpret_cast<const bf16x8*>((const bf16*)base + idx);
}

__device__ __forceinline__ float load1(const void* base, int idx, int f32) {
    return f32 ? ((const float*)base)[idx] : (float)((const bf16*)base)[idx];
}

// ---------------------------------------------------------------------------
// Kernel 1: QKV projection (MFMA) + RoPE (HW v_sin/v_cos) + fp32 norms +
// vectorized V transpose.  Dtype detection inlined per-block (bf16 N(0,1)
// never has exp field >= 134; fp32 mantissa halves hit it ~48%/elem);
// block 0 publishes the flag for the downstream kernels.
// ---------------------------------------------------------------------------
__global__ __launch_bounds__(64) void proj_rope_kernel(
    const void* __restrict__ q, const void* __restrict__ Wq,
    const void* __restrict__ Wk, const void* __restrict__ Wv,
    bf16* __restrict__ qh, bf16* __restrict__ kh, bf16* __restrict__ vt,
    float* __restrict__ qn, float* __restrict__ kn,
    int* __restrict__ flagw)
{
    const int lane = threadIdx.x;
    const int l16  = lane & 15;
    const int quad = lane >> 4;

    // inline dtype detection over q's first 1024 halfwords
    int hit = 0;
    const unsigned short* qu = (const unsigned short*)q;
#pragma unroll
    for (int i = 0; i < 16; ++i) {
        const unsigned short u = qu[lane + i * 64];
        if (((u >> 7) & 0xFF) >= 134) hit = 1;
    }
    const int f32 = (__ballot(hit) != 0ull) ? 1 : 0;
    if (blockIdx.x == 0 && lane == 0) *flagw = f32;

    int id = blockIdx.x;                 // ((w*BB + b)*(SS/16) + st)*HH + h
    const int h  = id % HH; id /= HH;
    const int st = id % (SS / 16); id /= (SS / 16);
    const int b  = id % BB; id /= BB;
    const int w  = id;                   // 0=q, 1=k, 2=v
    const int s0 = st * 16;

    const void* W = (w == 0) ? Wq : (w == 1) ? Wk : Wv;

    const size_t qrow = ((size_t)b * SS + s0 + l16) * DD;
    bf16x8 a0 = load8(q, qrow + quad * 8, f32);
    bf16x8 a1 = load8(q, qrow + quad * 8 + 32, f32);

    floatx4 cv[4];
#pragma unroll
    for (int t = 0; t < 4; ++t) {
        const size_t wrow = (size_t)(h * 64 + t * 16 + l16) * DD;
        bf16x8 b0 = load8(W, wrow + quad * 8, f32);
        bf16x8 b1 = load8(W, wrow + quad * 8 + 32, f32);
        floatx4 acc = {0.f, 0.f, 0.f, 0.f};
        acc = mfma16(a0, b0, acc);
        acc = mfma16(a1, b1, acc);
        cv[t] = acc;
    }

    const size_t bh = (size_t)b * HH + h;

    if (w < 2) {
        bf16*  dst  = (w == 0) ? qh : kh;
        float* ndst = (w == 0) ? qn : kn;
        float nacc[4] = {0.f, 0.f, 0.f, 0.f};
#pragma unroll
        for (int t = 0; t < 4; ++t) {
            const int d    = t * 16 + l16;
            const int twoi = d & ~1;
            const float frev = __builtin_amdgcn_exp2f(
                -(float)twoi * (13.2877123795f / 64.0f)) * 0.15915494309f;
            const bool odd = (d & 1);
#pragma unroll
            for (int r = 0; r < 4; ++r) {
                float v = cv[t][r];
                float partner = __shfl_xor(v, 1);
                const int srow = s0 + quad * 4 + r;
                float rev = (float)srow * frev;       // revolutions
                rev -= floorf(rev);
                float sn = __builtin_amdgcn_sinf(rev);
                float cs = __builtin_amdgcn_cosf(rev);
                float res = odd ? (partner * sn + v * cs)
                                : (v * cs - partner * sn);
                nacc[r] += res * res;                 // fp32 norm pre-rounding
                dst[(bh * SS + srow) * DD + d] = (bf16)res;
            }
        }
#pragma unroll
        for (int off = 1; off < 16; off <<= 1)
#pragma unroll
            for (int r = 0; r < 4; ++r)
                nacc[r] += __shfl_xor(nacc[r], off);
        if (l16 == 0)
#pragma unroll
            for (int r = 0; r < 4; ++r)
                ndst[bh * SS + s0 + quad * 4 + r] = nacc[r];
    } else {
        // V transposed (B,H,D,S); C-frag regs 0..3 = 4 consecutive s -> 8B store
#pragma unroll
        for (int t = 0; t < 4; ++t) {
            const int d = t * 16 + l16;
            bf16x4 pv;
#pragma unroll
            for (int r = 0; r < 4; ++r) pv[r] = (bf16)cv[t][r];
            *reinterpret_cast<bf16x4*>(vt + (bh * DD + d) * SS + s0 + quad * 4) = pv;
        }
    }
}

// ---------------------------------------------------------------------------
// Kernel 2: causal distance-kernel attention. Split-K (8 slots), compacted
// grid (no dead blocks). Per 16-key tile: S^T = K·Q^T via 16x16x32 MFMA; the
// S^T C-frag (row=key=quad*4+r, col=query=l16) IS the B-frag of
// v_mfma_f32_16x16x16_bf16 (k=quad*4+i, n=l16) -> exp'd scores feed PV
// directly from registers. No LDS, no bpermute, no barriers.
// O^T = V^T·P^T accumulated in C-frags (col=query, row=d). bf16 partials.
// ---------------------------------------------------------------------------
__global__ __launch_bounds__(64) void attn_kernel(
    const bf16* __restrict__ qh, const bf16* __restrict__ kh,
    const bf16* __restrict__ vt, const float* __restrict__ qn,
    const float* __restrict__ kn, const void* __restrict__ gamma,
    bf16* __restrict__ partial, const int* __restrict__ flagp,
    int ksh, int perbh)
{
    const int f32  = *flagp;
    const int lane = threadIdx.x;
    const int l16  = lane & 15;
    const int quad = lane >> 4;

    // compacted decode: group g has G qt-values x (g+1) slots, G = 2^(ksh-4)
    const int bh = blockIdx.x / perbh;
    int r = blockIdx.x - bh * perbh;
    const int G = 1 << (ksh - 4);
    int g = 0;
    while (r >= G * (g + 1)) { r -= G * (g + 1); ++g; }
    const int slot = r >> (ksh - 4);
    const int qt   = g * G + (r & (G - 1));
    const int s0   = qt * 16;
    const int tb   = slot << ksh;
    const int te   = min(tb + (1 << ksh), s0 + 16);
    const int nch  = (te - tb + 31) >> 5;           // 32-key chunks (2 tiles)
    const int h    = bh & 7;

    // p = exp(-gs*max(raw,0)) = exp2(min(-cc*raw, 0)),  cc = gs*log2(e) >= 0
    const float cc = load1(gamma, h, f32) * SCALE * 1.4426950408889634f;

    const bf16* qbase = qh + ((size_t)bh * SS + s0 + l16) * DD;
    bf16x8 aq0 = *reinterpret_cast<const bf16x8*>(qbase + quad * 8);
    bf16x8 aq1 = *reinterpret_cast<const bf16x8*>(qbase + quad * 8 + 32);
    const float qn_l = qn[(size_t)bh * SS + s0 + l16];

    floatx4 acc0 = {0.f,0.f,0.f,0.f}, acc1 = {0.f,0.f,0.f,0.f};
    floatx4 acc2 = {0.f,0.f,0.f,0.f}, acc3 = {0.f,0.f,0.f,0.f};

    const bf16*  kp  = kh + ((size_t)bh * SS + l16) * DD;   // + key*DD
    const float* knp = kn + (size_t)bh * SS + quad * 4;     // + key
    const bf16* vp0 = vt + ((size_t)bh * DD + l16) * SS + quad * 4;  // + key
    const bf16* vp1 = vp0 + (size_t)16 * SS;
    const bf16* vp2 = vp0 + (size_t)32 * SS;
    const bf16* vp3 = vp0 + (size_t)48 * SS;

    // preload chunk 0 (two 16-key tiles): K frags + kn
    bf16x8 kA0 = *reinterpret_cast<const bf16x8*>(kp + (size_t)tb * DD + quad * 8);
    bf16x8 kB0 = *reinterpret_cast<const bf16x8*>(kp + (size_t)tb * DD + quad * 8 + 32);
    bf16x8 kA1 = *reinterpret_cast<const bf16x8*>(kp + (size_t)(tb + 16) * DD + quad * 8);
    bf16x8 kB1 = *reinterpret_cast<const bf16x8*>(kp + (size_t)(tb + 16) * DD + quad * 8 + 32);
    float4 knv0 = *reinterpret_cast<const float4*>(knp + tb);
    float4 knv1 = *reinterpret_cast<const float4*>(knp + tb + 16);

    int t0 = tb;
    for (int c = 0; c < nch; ++c, t0 += 32) {
        const int t1 = t0 + 16;
        // V A-frags for both tiles (8B each), consumed at chunk end
        bf16x4 v00 = *reinterpret_cast<const bf16x4*>(vp0 + t0);
        bf16x4 v01 = *reinterpret_cast<const bf16x4*>(vp1 + t0);
        bf16x4 v02 = *reinterpret_cast<const bf16x4*>(vp2 + t0);
        bf16x4 v03 = *reinterpret_cast<const bf16x4*>(vp3 + t0);
        bf16x4 v10 = *reinterpret_cast<const bf16x4*>(vp0 + t1);
        bf16x4 v11 = *reinterpret_cast<const bf16x4*>(vp1 + t1);
        bf16x4 v12 = *reinterpret_cast<const bf16x4*>(vp2 + t1);
        bf16x4 v13 = *reinterpret_cast<const bf16x4*>(vp3 + t1);

        // prefetch next chunk's K + kn
        bf16x8 nA0, nB0, nA1, nB1; float4 nkn0, nkn1;
        if (c + 1 < nch) {
            const int tn = t0 + 32;
            nA0 = *reinterpret_cast<const bf16x8*>(kp + (size_t)tn * DD + quad * 8);
            nB0 = *reinterpret_cast<const bf16x8*>(kp + (size_t)tn * DD + quad * 8 + 32);
            nA1 = *reinterpret_cast<const bf16x8*>(kp + (size_t)(tn + 16) * DD + quad * 8);
            nB1 = *reinterpret_cast<const bf16x8*>(kp + (size_t)(tn + 16) * DD + quad * 8 + 32);
            nkn0 = *reinterpret_cast<const float4*>(knp + tn);
            nkn1 = *reinterpret_cast<const float4*>(knp + tn + 16);
        }

        // S^T for both tiles (independent chains)
        floatx4 z0 = {0.f,0.f,0.f,0.f};
        z0 = mfma16(kA0, aq0, z0);
        z0 = mfma16(kB0, aq1, z0);
        floatx4 z1 = {0.f,0.f,0.f,0.f};
        z1 = mfma16(kA1, aq0, z1);
        z1 = mfma16(kB1, aq1, z1);

        bf16x4 p0, p1;
        if (t1 + 15 <= s0) {                 // both tiles fully causal
#pragma unroll
            for (int i = 0; i < 4; ++i) {
                float rawA = fmaf(-2.f, z0[i], qn_l + ((const float*)&knv0)[i]);
                float rawB = fmaf(-2.f, z1[i], qn_l + ((const float*)&knv1)[i]);
                p0[i] = (bf16)__builtin_amdgcn_exp2f(fminf(-cc * rawA, 0.f));
                p1[i] = (bf16)__builtin_amdgcn_exp2f(fminf(-cc * rawB, 0.f));
            }
        } else {                             // general mask: key <= query
            const int dq0 = s0 + l16 - t0 - quad * 4;
            const int dq1 = dq0 - 16;
#pragma unroll
            for (int i = 0; i < 4; ++i) {
                float rawA = fmaf(-2.f, z0[i], qn_l + ((const float*)&knv0)[i]);
                float rawB = fmaf(-2.f, z1[i], qn_l + ((const float*)&knv1)[i]);
                float eA = __builtin_amdgcn_exp2f(fminf(-cc * rawA, 0.f));
                float eB = __builtin_amdgcn_exp2f(fminf(-cc * rawB, 0.f));
                p0[i] = (bf16)((i <= dq0) ? eA : 0.f);
                p1[i] = (bf16)((i <= dq1) ? eB : 0.f);
            }
        }

        // PV: scores feed B operand directly; V^T is A
        PV_MFMA(acc0, v00, p0);
        PV_MFMA(acc1, v01, p0);
        PV_MFMA(acc2, v02, p0);
        PV_MFMA(acc3, v03, p0);
        PV_MFMA(acc0, v10, p1);
        PV_MFMA(acc1, v11, p1);
        PV_MFMA(acc2, v12, p1);
        PV_MFMA(acc3, v13, p1);

        if (c + 1 < nch) {
            kA0 = nA0; kB0 = nB0; kA1 = nA1; kB1 = nB1;
            knv0 = nkn0; knv1 = nkn1;
        }
    }

    // cover MFMA-write -> read hazard (asm MFMAs are unmodeled by compiler)
    asm volatile("s_nop 7" : "+v"(acc0), "+v"(acc1), "+v"(acc2), "+v"(acc3));

    // O^T C-frag: col=query=l16, row=d_local=quad*4+r -> bf16x4 per nb
    bf16* pb = partial + (size_t)slot * PSLOT
             + ((size_t)bh * SS + s0 + l16) * DD + quad * 4;
    {
        bf16x4 o;
        o[0]=(bf16)acc0[0]; o[1]=(bf16)acc0[1]; o[2]=(bf16)acc0[2]; o[3]=(bf16)acc0[3];
        *reinterpret_cast<bf16x4*>(pb +  0) = o;
        o[0]=(bf16)acc1[0]; o[1]=(bf16)acc1[1]; o[2]=(bf16)acc1[2]; o[3]=(bf16)acc1[3];
        *reinterpret_cast<bf16x4*>(pb + 16) = o;
        o[0]=(bf16)acc2[0]; o[1]=(bf16)acc2[1]; o[2]=(bf16)acc2[2]; o[3]=(bf16)acc2[3];
        *reinterpret_cast<bf16x4*>(pb + 32) = o;
        o[0]=(bf16)acc3[0]; o[1]=(bf16)acc3[1]; o[2]=(bf16)acc3[2]; o[3]=(bf16)acc3[3];
        *reinterpret_cast<bf16x4*>(pb + 48) = o;
    }
}

// ---------------------------------------------------------------------------
// Kernel 3: fused split-K reduce + output projection. 256 threads/block;
// wave w handles column-tile ct=w (A re-reads hit L1). NACT templated.
// partial layout: [slot][b*8+h][s][d] bf16.
// ---------------------------------------------------------------------------
template <int NACT>
__device__ __forceinline__ floatx4 opj_core(const bf16* __restrict__ partial,
                                            const void* __restrict__ Wo,
                                            int b, int srow, size_t brow,
                                            int f32, int quad) {
    floatx4 acc = {0.f, 0.f, 0.f, 0.f};
#pragma unroll 4
    for (int kk = 0; kk < HD; kk += 32) {
        const int h  = kk >> 6;
        const int d0 = (kk & 63) + quad * 8;
        const bf16* ap = partial + (((size_t)(b * 8 + h)) * SS + srow) * 64 + d0;
        bf16x8 v0 = *reinterpret_cast<const bf16x8*>(ap);
        float u[8];
#pragma unroll
        for (int i = 0; i < 8; ++i) u[i] = (float)v0[i];
#pragma unroll
        for (int s = 1; s < NACT; ++s) {
            bf16x8 vs = *reinterpret_cast<const bf16x8*>(ap + (size_t)s * PSLOT);
#pragma unroll
            for (int i = 0; i < 8; ++i) u[i] += (float)vs[i];
        }
        bf16x8 a;
#pragma unroll
        for (int i = 0; i < 8; ++i) a[i] = (bf16)u[i];
        bf16x8 w = load8(Wo, brow + kk, f32);
        acc = mfma16(a, w, acc);
    }
    return acc;
}

__global__ __launch_bounds__(256) void outproj_kernel(
    const bf16* __restrict__ partial, const void* __restrict__ Wo,
    void* __restrict__ out, const int* __restrict__ flagp, int ksh)
{
    const int f32  = *flagp;
    const int ct   = threadIdx.x >> 6;
    const int lane = threadIdx.x & 63;
    const int l16  = lane & 15;
    const int quad = lane >> 4;

    const int g0   = blockIdx.x * 16;          // global row (b*SS + s)
    const int b    = g0 >> 11;
    const int s0   = g0 & (SS - 1);
    const int nact = (s0 >> ksh) + 1;
    const int srow = s0 + l16;
    const size_t brow = (size_t)(ct * 16 + l16) * HD + quad * 8;

    floatx4 acc;
    switch (nact) {
        case 1:  acc = opj_core<1>(partial, Wo, b, srow, brow, f32, quad); break;
        case 2:  acc = opj_core<2>(partial, Wo, b, srow, brow, f32, quad); break;
        case 3:  acc = opj_core<3>(partial, Wo, b, srow, brow, f32, quad); break;
        case 4:  acc = opj_core<4>(partial, Wo, b, srow, brow, f32, quad); break;
        case 5:  acc = opj_core<5>(partial, Wo, b, srow, brow, f32, quad); break;
        case 6:  acc = opj_core<6>(partial, Wo, b, srow, brow, f32, quad); break;
        case 7:  acc = opj_core<7>(partial, Wo, b, srow, brow, f32, quad); break;
        default: acc = opj_core<8>(partial, Wo, b, srow, brow, f32, quad); break;
    }

#pragma unroll
    for (int r = 0; r < 4; ++r) {
        const size_t o = (size_t)(g0 + quad * 4 + r) * DD + ct * 16 + l16;
        if (f32) ((float*)out)[o] = acc[r];
        else     ((bf16*)out)[o]  = (bf16)acc[r];
    }
}

// ---------------------------------------------------------------------------
extern "C" void kernel_launch(void* const* d_in, const int* in_sizes, int n_in,
                              void* d_out, int out_size, void* d_ws, size_t ws_size,
                              hipStream_t stream) {
    const void* q     = d_in[0];
    const void* Wq    = d_in[1];
    const void* Wk    = d_in[2];
    const void* Wv    = d_in[3];
    const void* Wo    = d_in[4];
    const void* gamma = d_in[5];

    char* ws = (char*)d_ws;
    bf16*  qh      = (bf16*)(ws);                    // 4 MiB
    bf16*  kh      = (bf16*)(ws + 4194304);          // 4 MiB
    bf16*  vt      = (bf16*)(ws + 8388608);          // 4 MiB
    float* qn      = (float*)(ws + 12582912);        // 128 KiB
    float* kn      = (float*)(ws + 12713984);        // 128 KiB
    int*   flag    = (int*)  (ws + 12845056);
    bf16*  partial = (bf16*)(ws + 13631488);         // nslot x 4 MiB (bf16)

    // split-K tier by available workspace: 8 / 4 / 2 / 1 slots
    int ksh = 11;
    const size_t base = 13631488ull;
    if      (ws_size >= base + 8ull * 4194304) ksh = 8;
    else if (ws_size >= base + 4ull * 4194304) ksh = 9;
    else if (ws_size >= base + 2ull * 4194304) ksh = 10;

    const int G = 1 << (ksh - 4);
    const int n = 128 / G;                           // slot-groups
    const int perbh = G * n * (n + 1) / 2;           // active (qt,slot) per bh

    proj_rope_kernel<<<dim3(3 * BB * (SS / 16) * HH), dim3(64), 0, stream>>>(
        q, Wq, Wk, Wv, qh, kh, vt, qn, kn, flag);
    attn_kernel<<<dim3(BB * HH * perbh), dim3(64), 0, stream>>>(
        qh, kh, vt, qn, kn, gamma, partial, flag, ksh, perbh);
    outproj_kernel<<<dim3(BB * SS / 16), dim3(256), 0, stream>>>(
        partial, Wo, d_out, flag, ksh);
}